// Round 1
// baseline (373.288 us; speedup 1.0000x reference)
//
#include <hip/hip_runtime.h>
#include <math.h>

#define Bc 4
#define Lc 1024
#define Sc 1024
#define Hc 16
#define Ec 64
#define BHc 64
#define NF 513      // S/2 + 1
#define TOPK 10
#define ECH 8       // e-columns per FFT block
#define NCH 8       // chunks per bh (ECH*NCH = 64 = E)

// ---------------------------------------------------------------------------
// Kernel 1: per-(bh, e-chunk) radix-2 FFT (N=1024) in LDS, writes partial
// magnitude sums (over ECH columns) to pmag[blk][f].
// ---------------------------------------------------------------------------
__global__ __launch_bounds__(512) void fft_chunk_kernel(
    const float* __restrict__ keys, float* __restrict__ pmag) {
  // stride 1025 float2 (2050 words) de-correlates column base addresses
  // across banks for the bit-reversed scatter writes.
  __shared__ float2 data[ECH][1025];
  __shared__ float2 tw[512];      // tw[m] = exp(-2*pi*i*m/1024)

  const int t   = threadIdx.x;
  const int blk = blockIdx.x;       // ch*64 + bh
  const int bh  = blk & 63;
  const int ch  = blk >> 6;
  const int b   = bh >> 4, h = bh & 15;
  const int e0  = ch * ECH;

  // twiddle table (one entry per thread, 512 threads exactly)
  {
    float ang = -6.28318530717958647692f * (float)t / 1024.0f;
    float sn, cs;
    sincosf(ang, &sn, &cs);
    tw[t] = make_float2(cs, sn);
  }

  // load with bit-reversal, imag = 0
  for (int i = t; i < ECH * 1024; i += 512) {
    int e = i & (ECH - 1);
    int s = i >> 3;                 // ECH == 8
    float v = keys[(((size_t)b * Sc + s) * Hc + h) * Ec + e0 + e];
    int rs = __brev((unsigned)s) >> 22;   // 10-bit reverse
    data[e][rs] = make_float2(v, 0.0f);
  }
  __syncthreads();

  // 10 radix-2 stages; 512 butterflies per column, thread t owns butterfly t
  for (int st = 0; st < 10; ++st) {
    const int half = 1 << st;
    const int j  = t & (half - 1);
    const int i0 = ((t >> st) << (st + 1)) + j;
    const int i1 = i0 + half;
    const float2 W = tw[j << (9 - st)];
#pragma unroll
    for (int col = 0; col < ECH; ++col) {
      float2 u = data[col][i0];
      float2 v = data[col][i1];
      float vr = v.x * W.x - v.y * W.y;
      float vi = v.x * W.y + v.y * W.x;
      data[col][i0] = make_float2(u.x + vr, u.y + vi);
      data[col][i1] = make_float2(u.x - vr, u.y - vi);
    }
    __syncthreads();
  }

  // partial magnitude sums over this chunk's ECH columns
  for (int f = t; f < NF; f += 512) {
    float ssum = 0.0f;
#pragma unroll
    for (int c = 0; c < ECH; ++c) {
      float2 z = data[c][f];
      ssum += sqrtf(z.x * z.x + z.y * z.y);
    }
    pmag[(size_t)blk * NF + f] = ssum;
  }
}

// ---------------------------------------------------------------------------
// Kernel 2: per-bh top-10 (value desc, ties -> lower index, like lax.top_k)
// ---------------------------------------------------------------------------
__global__ __launch_bounds__(256) void topk_kernel(
    const float* __restrict__ pmag, int* __restrict__ idx_out) {
  __shared__ float mag[NF];
  __shared__ float redv[4];
  __shared__ int   redi[4];
  __shared__ int   topi[TOPK];

  const int bh = blockIdx.x;
  const int t  = threadIdx.x;

  for (int f = t; f < NF; f += 256) {
    float s = 0.0f;
#pragma unroll
    for (int ch = 0; ch < NCH; ++ch)
      s += pmag[(size_t)(ch * 64 + bh) * NF + f];
    mag[f] = s;
  }
  __syncthreads();

  for (int r = 0; r < TOPK; ++r) {
    float bv = -INFINITY;
    int   bi = 0x7fffffff;
    for (int f = t; f < NF; f += 256) {
      float v = mag[f];
      if (v > bv || (v == bv && f < bi)) { bv = v; bi = f; }
    }
#pragma unroll
    for (int off = 32; off > 0; off >>= 1) {
      float ov = __shfl_xor(bv, off);
      int   oi = __shfl_xor(bi, off);
      if (ov > bv || (ov == bv && oi < bi)) { bv = ov; bi = oi; }
    }
    if ((t & 63) == 0) { redv[t >> 6] = bv; redi[t >> 6] = bi; }
    __syncthreads();
    if (t == 0) {
      for (int w = 1; w < 4; ++w)
        if (redv[w] > bv || (redv[w] == bv && redi[w] < bi)) {
          bv = redv[w]; bi = redi[w];
        }
      topi[r] = bi;
      mag[bi] = -INFINITY;
    }
    __syncthreads();
  }
  if (t < TOPK) idx_out[bh * 16 + t] = topi[t];
}

// ---------------------------------------------------------------------------
// Kernel 3: sparse attention. Per (bh): 10 selected K/V rows in registers
// (lane = e). Per query row: 10 dots -> wave allreduce -> softmax(10) ->
// out = sum p_j * V_j. attn row written as full zeros+scatter via per-wave
// LDS row buffer with coalesced float4 streaming stores.
// ---------------------------------------------------------------------------
__global__ __launch_bounds__(256) void attn_kernel(
    const float* __restrict__ qs, const float* __restrict__ ks,
    const float* __restrict__ vs, const int* __restrict__ idx,
    float* __restrict__ out, float* __restrict__ attn) {
  __shared__ float prow[4][1024];

  const int bh   = blockIdx.x;
  const int b    = bh >> 4, h = bh & 15;
  const int l0   = blockIdx.y * 64;
  const int lane = threadIdx.x & 63;
  const int wave = threadIdx.x >> 6;

  for (int i = threadIdx.x; i < 4 * 1024; i += 256)
    (&prow[0][0])[i] = 0.0f;

  int id[TOPK];
  float kreg[TOPK], vreg[TOPK];
#pragma unroll
  for (int j = 0; j < TOPK; ++j) {
    id[j] = idx[bh * 16 + j];
    size_t base = (((size_t)b * Sc + id[j]) * Hc + h) * Ec + lane;
    kreg[j] = ks[base];
    vreg[j] = vs[base];
  }
  int myid = 0;
#pragma unroll
  for (int j = 0; j < TOPK; ++j) myid = (lane == j) ? id[j] : myid;
  __syncthreads();

  for (int li = 0; li < 16; ++li) {
    const int l = l0 + wave * 16 + li;
    float q = qs[(((size_t)b * Lc + l) * Hc + h) * Ec + lane];

    float p[TOPK];
#pragma unroll
    for (int j = 0; j < TOPK; ++j) p[j] = q * kreg[j];
#pragma unroll
    for (int j = 0; j < TOPK; ++j) {
      float v = p[j];
#pragma unroll
      for (int off = 32; off > 0; off >>= 1) v += __shfl_xor(v, off);
      p[j] = v * 0.125f;   // * 1/sqrt(64)
    }
    float mx = p[0];
#pragma unroll
    for (int j = 1; j < TOPK; ++j) mx = fmaxf(mx, p[j]);
    float ssum = 0.0f;
#pragma unroll
    for (int j = 0; j < TOPK; ++j) { p[j] = __expf(p[j] - mx); ssum += p[j]; }
    float inv = 1.0f / ssum;
    float o = 0.0f;
#pragma unroll
    for (int j = 0; j < TOPK; ++j) { p[j] *= inv; o = fmaf(p[j], vreg[j], o); }

    out[(((size_t)b * Lc + l) * Hc + h) * Ec + lane] = o;

    // attn row: scatter 10 probs into per-wave LDS row, stream out as float4
    float myp = 0.0f;
#pragma unroll
    for (int j = 0; j < TOPK; ++j) myp = (lane == j) ? p[j] : myp;
    if (lane < TOPK) prow[wave][myid] = myp;

    float* arow = attn + ((size_t)bh * Lc + l) * Sc;
#pragma unroll
    for (int i = 0; i < 4; ++i) {
      float4 vv = ((const float4*)&prow[wave][0])[lane + 64 * i];
      ((float4*)arow)[lane + 64 * i] = vv;
    }
    if (lane < TOPK) prow[wave][myid] = 0.0f;   // restore zeros for next row
  }
}

// ---------------------------------------------------------------------------
extern "C" void kernel_launch(void* const* d_in, const int* in_sizes, int n_in,
                              void* d_out, int out_size, void* d_ws,
                              size_t ws_size, hipStream_t stream) {
  (void)in_sizes; (void)n_in; (void)out_size; (void)ws_size;
  const float* qs = (const float*)d_in[0];
  const float* ks = (const float*)d_in[1];
  const float* vs = (const float*)d_in[2];

  float* out  = (float*)d_out;
  float* attn = out + (size_t)Bc * Lc * Hc * Ec;   // outputs concatenated

  float* pmag = (float*)d_ws;                               // 512*513 f32
  int*   idxs = (int*)((char*)d_ws +
                       (size_t)(NCH * BHc) * NF * sizeof(float));

  fft_chunk_kernel<<<NCH * BHc, 512, 0, stream>>>(ks, pmag);
  topk_kernel<<<BHc, 256, 0, stream>>>(pmag, idxs);
  attn_kernel<<<dim3(BHc, 16), 256, 0, stream>>>(qs, ks, vs, idxs, out, attn);
}

// Round 6
// 355.924 us; speedup vs baseline: 1.0488x; 1.0488x over previous
//
#include <hip/hip_runtime.h>
#include <math.h>

#define Bc 4
#define Lc 1024
#define Sc 1024
#define Hc 16
#define Ec 64
#define BHc 64
#define NF 513
#define TOPK 10
#define NCH 8            // chunks per bh; each chunk = 8 real cols = 4 complex
#define COLW 2304        // padded words per complex column (2048 + pad)

// padded LDS word address for complex index i within a column
#define PADW(w) ((w) + (((w) >> 4) << 1))
#define ZADDR(col, i) ((col) * COLW + PADW(2 * (i)))

// ---------------------------------------------------------------------------
// Kernel 1: per-(bh, 8-real-col chunk): 4 packed complex radix-4 FFTs (N=1024)
// in LDS; unpack via conjugate symmetry; write partial |X| sums to pmag.
// ---------------------------------------------------------------------------
__global__ __launch_bounds__(512) void fft4_kernel(
    const float* __restrict__ keys, float* __restrict__ pmag) {
  __shared__ float zbuf[4 * COLW];
  __shared__ float2 tw[1024];

  const int t   = threadIdx.x;
  const int blk = blockIdx.x;        // ch*64 + bh
  const int bh  = blk & 63;
  const int ch  = blk >> 6;
  const int b   = bh >> 4, h = bh & 15;

  // twiddles: tw[m] = exp(-2*pi*i*m/1024)
  for (int m = t; m < 1024; m += 512) {
    float sn, cs;
    sincosf(-6.28318530717958647692f * (float)m * (1.0f / 1024.0f), &sn, &cs);
    tw[m] = make_float2(cs, sn);
  }

  // load: float4 = 4 real cols = 2 complex cols; digit-4-reversed scatter
  const float4* k4 = (const float4*)keys;
  const int fbase = b * 262144 + h * 16 + ch * 2;   // float4 index base
  for (int i = t; i < 2048; i += 512) {
    const int s  = i >> 1;
    const int q4 = i & 1;
    float4 v = k4[fbase + s * 256 + q4];
    unsigned r = __brev((unsigned)s) >> 22;                  // 10-bit bitrev
    unsigned rs = ((r & 0x2AAu) >> 1) | ((r & 0x155u) << 1); // digit-4 rev
    *(float2*)&zbuf[ZADDR(2 * q4, rs)]     = make_float2(v.x, v.y);
    *(float2*)&zbuf[ZADDR(2 * q4 + 1, rs)] = make_float2(v.z, v.w);
  }
  __syncthreads();

  // 5 radix-4 stages; 1024 butterflies/stage (4 cols x 256), 2 per thread
  for (int st = 0; st < 5; ++st) {
    const int quarter = 1 << (2 * st);
    const int tstep   = 256 >> (2 * st);
#pragma unroll
    for (int rep = 0; rep < 2; ++rep) {
      const int task = t + rep * 512;
      const int col  = task >> 8;
      const int bf   = task & 255;
      const int j    = bf & (quarter - 1);
      const int bas  = ((bf >> (2 * st)) << (2 * st + 2)) + j;

      const float2 w1 = tw[j * tstep];
      const float2 w2 = tw[2 * j * tstep];
      const float2 w3 = tw[3 * j * tstep];

      float2 a  = *(const float2*)&zbuf[ZADDR(col, bas)];
      float2 bb = *(const float2*)&zbuf[ZADDR(col, bas + quarter)];
      float2 c  = *(const float2*)&zbuf[ZADDR(col, bas + 2 * quarter)];
      float2 d  = *(const float2*)&zbuf[ZADDR(col, bas + 3 * quarter)];

      float2 bw = make_float2(bb.x * w1.x - bb.y * w1.y, bb.x * w1.y + bb.y * w1.x);
      float2 cw = make_float2(c.x * w2.x - c.y * w2.y, c.x * w2.y + c.y * w2.x);
      float2 dw = make_float2(d.x * w3.x - d.y * w3.y, d.x * w3.y + d.y * w3.x);

      float2 s0 = make_float2(a.x + cw.x, a.y + cw.y);   // a + c'
      float2 s1 = make_float2(a.x - cw.x, a.y - cw.y);   // a - c'
      float2 s2 = make_float2(bw.x + dw.x, bw.y + dw.y); // b' + d'
      float2 s3 = make_float2(bw.x - dw.x, bw.y - dw.y); // b' - d'

      *(float2*)&zbuf[ZADDR(col, bas)]               = make_float2(s0.x + s2.x, s0.y + s2.y);
      *(float2*)&zbuf[ZADDR(col, bas + quarter)]     = make_float2(s1.x + s3.y, s1.y - s3.x); // s1 - i*s3
      *(float2*)&zbuf[ZADDR(col, bas + 2 * quarter)] = make_float2(s0.x - s2.x, s0.y - s2.y);
      *(float2*)&zbuf[ZADDR(col, bas + 3 * quarter)] = make_float2(s1.x - s3.y, s1.y + s3.x); // s1 + i*s3
    }
    __syncthreads();
  }

  // unpack 2 reals per complex col, accumulate |X| over the chunk's 8 cols
  for (int f = t; f < NF; f += 512) {
    const int nf = (1024 - f) & 1023;
    float ssum = 0.0f;
#pragma unroll
    for (int c = 0; c < 4; ++c) {
      float2 zf = *(const float2*)&zbuf[ZADDR(c, f)];
      float2 zn = *(const float2*)&zbuf[ZADDR(c, nf)];
      float xr = 0.5f * (zf.x + zn.x);
      float xi = 0.5f * (zf.y - zn.y);
      float yr = 0.5f * (zf.y + zn.y);
      float yi = 0.5f * (zn.x - zf.x);
      ssum += sqrtf(xr * xr + xi * xi) + sqrtf(yr * yr + yi * yi);
    }
    pmag[(size_t)blk * NF + f] = ssum;
  }
}

// ---------------------------------------------------------------------------
// Kernel 2: per-bh top-10, single wave (value desc, ties -> lower index)
// ---------------------------------------------------------------------------
__global__ __launch_bounds__(64) void topk_kernel(
    const float* __restrict__ pmag, int* __restrict__ idx_out) {
  __shared__ float mag[NF];
  const int bh = blockIdx.x;
  const int t  = threadIdx.x;

  for (int f = t; f < NF; f += 64) {
    float s = 0.0f;
#pragma unroll
    for (int ch = 0; ch < NCH; ++ch)
      s += pmag[(size_t)(ch * 64 + bh) * NF + f];
    mag[f] = s;
  }
  __syncthreads();

  for (int r = 0; r < TOPK; ++r) {
    float bv = -INFINITY;
    int   bi = 0x7fffffff;
    for (int f = t; f < NF; f += 64) {
      float v = mag[f];
      if (v > bv || (v == bv && f < bi)) { bv = v; bi = f; }
    }
#pragma unroll
    for (int off = 32; off > 0; off >>= 1) {
      float ov = __shfl_xor(bv, off);
      int   oi = __shfl_xor(bi, off);
      if (ov > bv || (ov == bv && oi < bi)) { bv = ov; bi = oi; }
    }
    if (t == 0) {
      idx_out[bh * 16 + r] = bi;
      mag[bi] = -INFINITY;
    }
    __syncthreads();
  }
}

// ---------------------------------------------------------------------------
// Kernel 3: sparse attention, no shuffle reductions.
//   A: stage Q-tile(64x64), K/V-sel(10x64) in LDS
//   B: one dot per thread (q from LDS stride-65: conflict-free; k broadcast)
//   C: softmax row per thread
//   D: per wave: out row + attn row (LDS row buffer -> float4 stream)
// ---------------------------------------------------------------------------
__global__ __launch_bounds__(256) void attn_kernel(
    const float* __restrict__ qs, const float* __restrict__ ks,
    const float* __restrict__ vs, const int* __restrict__ idx,
    float* __restrict__ out, float* __restrict__ attn) {
  __shared__ float qt[64][65];
  __shared__ float kvt[2][TOPK][64];
  __shared__ float sc[64][13];
  __shared__ int   sid[TOPK];
  __shared__ float prow[4][1024];

  const int t    = threadIdx.x;
  const int bh   = blockIdx.x;
  const int b    = bh >> 4, h = bh & 15;
  const int l0   = blockIdx.y * 64;
  const int wave = t >> 6;
  const int lane = t & 63;

  if (t < TOPK) sid[t] = idx[bh * 16 + t];
  for (int i = t; i < 4 * 1024; i += 256) (&prow[0][0])[i & 4095] = 0.0f;

  // Q tile: coalesced float4 loads, scalar LDS stores (row pad 65)
  {
    const float4* q4 = (const float4*)qs;
    const int fb = b * 262144 + h * 16;   // float4 index base
    for (int i = t; i < 1024; i += 256) {
      const int row = i >> 4, c4 = i & 15;
      float4 v = q4[fb + (l0 + row) * 256 + c4];
      qt[row][c4 * 4 + 0] = v.x;
      qt[row][c4 * 4 + 1] = v.y;
      qt[row][c4 * 4 + 2] = v.z;
      qt[row][c4 * 4 + 3] = v.w;
    }
  }
  __syncthreads();   // sid ready

  // K/V selected rows
  for (int i = t; i < 2 * TOPK * 64; i += 256) {
    const int kv = i >= TOPK * 64;
    const int j  = (i >> 6) - kv * TOPK;
    const int e  = i & 63;
    const float* src = kv ? vs : ks;
    kvt[kv][j][e] = src[(size_t)b * 1048576 + (size_t)sid[j] * 1024 + h * 64 + e];
  }
  __syncthreads();

  // scores: one dot per thread
#pragma unroll
  for (int r = 0; r < 3; ++r) {
    const int task = r * 256 + t;
    const int j = task >> 6;
    const int l = task & 63;
    if (j < TOPK) {
      float acc = 0.0f;
#pragma unroll 8
      for (int e = 0; e < 64; ++e) acc += qt[l][e] * kvt[0][j][e];
      sc[l][j] = acc * 0.125f;
    }
  }
  __syncthreads();

  // softmax: one row per thread
  if (t < 64) {
    float pv[TOPK];
    float mx = -INFINITY;
#pragma unroll
    for (int j = 0; j < TOPK; ++j) { pv[j] = sc[t][j]; mx = fmaxf(mx, pv[j]); }
    float sum = 0.0f;
#pragma unroll
    for (int j = 0; j < TOPK; ++j) { pv[j] = __expf(pv[j] - mx); sum += pv[j]; }
    float inv = 1.0f / sum;
#pragma unroll
    for (int j = 0; j < TOPK; ++j) sc[t][j] = pv[j] * inv;
  }
  __syncthreads();

  // out + attn rows, per wave (16 rows each)
  for (int li = 0; li < 16; ++li) {
    const int l = wave * 16 + li;

    float o = 0.0f;
#pragma unroll
    for (int j = 0; j < TOPK; ++j) o += sc[l][j] * kvt[1][j][lane];
    out[((size_t)b * 1024 + l0 + l) * 1024 + h * 64 + lane] = o;

    if (lane < TOPK) prow[wave][sid[lane]] = sc[l][lane];

    float* arow = attn + ((size_t)bh * 1024 + l0 + l) * 1024;
#pragma unroll
    for (int i = 0; i < 4; ++i) {
      float4 vv = *(const float4*)&prow[wave][4 * lane + 256 * i];
      *(float4*)&arow[4 * lane + 256 * i] = vv;
    }
    if (lane < TOPK) prow[wave][sid[lane]] = 0.0f;
  }
}

// ---------------------------------------------------------------------------
extern "C" void kernel_launch(void* const* d_in, const int* in_sizes, int n_in,
                              void* d_out, int out_size, void* d_ws,
                              size_t ws_size, hipStream_t stream) {
  (void)in_sizes; (void)n_in; (void)out_size; (void)ws_size;
  const float* qs = (const float*)d_in[0];
  const float* ks = (const float*)d_in[1];
  const float* vs = (const float*)d_in[2];

  float* out  = (float*)d_out;
  float* attn = out + (size_t)Bc * Lc * Hc * Ec;

  float* pmag = (float*)d_ws;                                   // 512*513 f32
  int*   idxs = (int*)((char*)d_ws + (size_t)(NCH * BHc) * NF * sizeof(float));

  fft4_kernel<<<NCH * BHc, 512, 0, stream>>>(ks, pmag);
  topk_kernel<<<BHc, 64, 0, stream>>>(pmag, idxs);
  attn_kernel<<<dim3(BHc, 16), 256, 0, stream>>>(qs, ks, vs, idxs, out, attn);
}